// Round 4
// baseline (37.997 us; speedup 1.0000x reference)
//
#include <hip/hip_runtime.h>

typedef _Float16 half4_t __attribute__((ext_vector_type(4)));
typedef _Float16 half8_t __attribute__((ext_vector_type(8)));
typedef float    f32x4   __attribute__((ext_vector_type(4)));

#define NG   4000
#define EPG  512
#define LDH  76   // halves; 152 B = 38 dwords == 6 mod 32 -> conflict-free b64 row-fragment reads

// ---- prep: pack W (3 x [64][64] f32, row-major k x c) into MFMA B-fragment order ----
// wb[layer][f = c0tile*2 + ktile][lane][8]  (f16)
__global__ __launch_bounds__(256) void prep_wb(const float* __restrict__ W1,
                                               const float* __restrict__ W2,
                                               const float* __restrict__ W3,
                                               _Float16* __restrict__ wb) {
    int e = blockIdx.x * 256 + threadIdx.x;     // 0..1535
    if (e >= 1536) return;
    int layer = e >> 9, rem = e & 511, f = rem >> 6, l = rem & 63;
    const float* W = layer == 0 ? W1 : (layer == 1 ? W2 : W3);
    int c  = (f >> 1) * 16 + (l & 15);
    int kb = (f & 1) * 32 + 4 * (l >> 4);
    half8_t v;
    #pragma unroll
    for (int j = 0; j < 4; ++j) v[j]     = (_Float16)W[(kb + j) * 64 + c];
    #pragma unroll
    for (int j = 0; j < 4; ++j) v[4 + j] = (_Float16)W[(kb + 16 + j) * 64 + c];
    *(half8_t*)(wb + (size_t)e * 8) = v;
}

// row-fragment load from padded row-major LDS: elems 0-3 = k kb..kb+3, elems 4-7 = kb+16..kb+19
__device__ inline half8_t ldsfrag(const _Float16* base, int row, int kb) {
    half4_t lo = *(const half4_t*)(base + row * LDH + kb);
    half4_t hi = *(const half4_t*)(base + row * LDH + kb + 16);
    return __builtin_shufflevector(lo, hi, 0, 1, 2, 3, 4, 5, 6, 7);
}

// one GCN layer, in-place: Hl = H @ W (in-register) ; H = A_hat @ Hl + b
template <bool LAST>
__device__ inline float layer2(const _Float16* __restrict__ wbl,
                               const float* __restrict__ bias,
                               _Float16* H, const _Float16* AfP,
                               int lane, int w) {
    const int l15 = lane & 15, lg = lane >> 4;
    const int c0 = 16 * w;

    // W B-fragments for this wave's c-strip (global, L1-hot)
    half8_t wf0 = *(const half8_t*)(wbl + ((size_t)(w * 2 + 0) * 64 + lane) * 8);
    half8_t wf1 = *(const half8_t*)(wbl + ((size_t)(w * 2 + 1) * 64 + lane) * 8);
    const float bv = bias[c0 + l15];

    // GEMM1: D1[s][c0-strip], 4 s-tiles, K=64  (each wave reads ALL of H)
    f32x4 acc1[4];
    #pragma unroll
    for (int st = 0; st < 4; ++st) {
        const int row = 16 * st + l15;
        half8_t a0 = ldsfrag(H, row, 4 * lg);        // k 0..31
        half8_t a1 = ldsfrag(H, row, 32 + 4 * lg);   // k 32..63
        f32x4 acc = {0.f, 0.f, 0.f, 0.f};
        acc = __builtin_amdgcn_mfma_f32_16x16x32_f16(a0, wf0, acc, 0, 0, 0);
        acc = __builtin_amdgcn_mfma_f32_16x16x32_f16(a1, wf1, acc, 0, 0, 0);
        acc1[st] = acc;
    }

    // in-register: D1 fragments -> GEMM2 B-fragments (k = s)
    half8_t bf0, bf1;
    #pragma unroll
    for (int j = 0; j < 4; ++j) {
        bf0[j]     = (_Float16)acc1[0][j];   // s = 4*lg + j
        bf0[4 + j] = (_Float16)acc1[1][j];   // s = 16 + 4*lg + j
        bf1[j]     = (_Float16)acc1[2][j];   // s = 32 + 4*lg + j
        bf1[4 + j] = (_Float16)acc1[3][j];   // s = 48 + 4*lg + j
    }

    if (!LAST) __syncthreads();   // all H reads done before in-place overwrite

    // GEMM2: H[d][c0-strip] = A_hat @ Hl (+ bias), 4 d-tiles
    float ps = 0.f;
    #pragma unroll
    for (int dt = 0; dt < 4; ++dt) {
        half8_t f0 = *(const half8_t*)(AfP + ((size_t)(dt * 2 + 0) * 64 + lane) * 8);
        half8_t f1 = *(const half8_t*)(AfP + ((size_t)(dt * 2 + 1) * 64 + lane) * 8);
        f32x4 acc = {0.f, 0.f, 0.f, 0.f};
        acc = __builtin_amdgcn_mfma_f32_16x16x32_f16(f0, bf0, acc, 0, 0, 0);
        acc = __builtin_amdgcn_mfma_f32_16x16x32_f16(f1, bf1, acc, 0, 0, 0);
        if (LAST) {
            #pragma unroll
            for (int r = 0; r < 4; ++r) ps += acc[r];
        } else {
            #pragma unroll
            for (int r = 0; r < 4; ++r)
                H[(16 * dt + 4 * lg + r) * LDH + c0 + l15] = (_Float16)(acc[r] + bv);
        }
    }
    if (LAST) ps += 16.f * bv;
    else __syncthreads();         // H' visible before next layer's GEMM1
    return ps;
}

__global__ __launch_bounds__(256, 8) void gcn3_mfma3(
    const float* __restrict__ x, const int* __restrict__ ei,
    const _Float16* __restrict__ wb,
    const float* __restrict__ b1, const float* __restrict__ b2,
    const float* __restrict__ b3,
    float* __restrict__ y, int etot)
{
    __shared__ __align__(16) char smem[18432];
    _Float16* H      = (_Float16*)(smem);           // [64][76] f16 = 9728 B
    _Float16* AfP    = (_Float16*)(smem + 9728);    // A_hat packed A-frags [8][64][8] f16 = 8192 B
    int*      Aint16 = (int*)(smem + 9728);         // [64][32] packed u16x2 counts (aliases AfP)
    float*    dinv   = (float*)(smem + 17920);      // [64]
    float*    red    = (float*)(smem + 18176);      // [4]

    const int g = blockIdx.x, t = threadIdx.x;
    const int lane = t & 63, w = t >> 6;
    const int base = g * 64;

    // edges -> registers (2 per thread)
    const int* srcp = ei + (size_t)g * EPG;
    const int* dstp = ei + (size_t)etot + (size_t)g * EPG;
    const int2 sv = *(const int2*)(srcp + 2 * t);
    const int2 dv = *(const int2*)(dstp + 2 * t);
    const int sa = sv.x - base, da = dv.x - base;
    const int sb = sv.y - base, db = dv.y - base;

    {   // zero Aint16 (2048 ints)
        int4 z = {0, 0, 0, 0};
        int4* A4 = (int4*)Aint16;
        A4[t] = z; A4[t + 256] = z;
    }
    // x -> H (f32 -> f16, padded rows; row stride 38 dw == 6 mod 32 -> conflict-free)
    const float4* xg = (const float4*)(x + (size_t)g * 4096);
    float4 xr[4];
    #pragma unroll
    for (int it = 0; it < 4; ++it) xr[it] = xg[t + 256 * it];
    #pragma unroll
    for (int it = 0; it < 4; ++it) {
        const int e4 = t + 256 * it;
        const int row = e4 >> 4, col = (e4 & 15) * 4;
        half4_t hv = {(_Float16)xr[it].x, (_Float16)xr[it].y,
                      (_Float16)xr[it].z, (_Float16)xr[it].w};
        *(half4_t*)(H + row * LDH + col) = hv;
    }
    __syncthreads();

    // adjacency counts, packed 2 per int (deterministic integer atomics)
    atomicAdd(&Aint16[da * 32 + (sa >> 1)], 1 << ((sa & 1) * 16));
    atomicAdd(&Aint16[db * 32 + (sb >> 1)], 1 << ((sb & 1) * 16));
    __syncthreads();

    // degree = row-sum of packed counts (no carries: lo-sum <= 512)
    {
        const int d = t >> 2, qq = t & 3;
        const int* rowp = Aint16 + d * 32 + qq * 8;
        const int4 a = *(const int4*)(rowp);
        const int4 b = *(const int4*)(rowp + 4);
        int p = a.x + a.y + a.z + a.w + b.x + b.y + b.z + b.w;
        p += __shfl_down(p, 2, 4);
        p += __shfl_down(p, 1, 4);
        if (qq == 0) {
            const int degv = (p & 0xffff) + (p >> 16);
            dinv[d] = rsqrtf((float)(degv + 1));   // +1 = self-loop
        }
    }

    // stage Aint16 reads for AfP pack (AfP aliases Aint16)
    int2 c0a[2], c1a[2];
    #pragma unroll
    for (int q = 0; q < 2; ++q) {
        const int e = t + 256 * q, f = e >> 6, l = e & 63;
        const int d  = (f >> 1) * 16 + (l & 15);
        const int kb = (f & 1) * 32 + 4 * (l >> 4);
        c0a[q] = *(const int2*)(Aint16 + d * 32 + (kb >> 1));
        c1a[q] = *(const int2*)(Aint16 + d * 32 + ((kb + 16) >> 1));
    }
    __syncthreads();   // dinv visible; all Aint16 reads done before AfP writes

    #pragma unroll
    for (int q = 0; q < 2; ++q) {
        const int e = t + 256 * q, f = e >> 6, l = e & 63;
        const int d  = (f >> 1) * 16 + (l & 15);
        const int kb = (f & 1) * 32 + 4 * (l >> 4);
        const float dr = dinv[d];
        const int* cp0 = (const int*)&c0a[q];
        const int* cp1 = (const int*)&c1a[q];
        half8_t hv;
        #pragma unroll
        for (int j = 0; j < 4; ++j) {
            const int v = cp0[j >> 1];
            const int cnt = (j & 1) ? ((v >> 16) & 0xffff) : (v & 0xffff);
            const int s = kb + j;
            float val = (float)cnt * dr * dinv[s];
            if (d == s) val += dr * dr;
            hv[j] = (_Float16)val;
        }
        #pragma unroll
        for (int j = 0; j < 4; ++j) {
            const int v = cp1[j >> 1];
            const int cnt = (j & 1) ? ((v >> 16) & 0xffff) : (v & 0xffff);
            const int s = kb + 16 + j;
            float val = (float)cnt * dr * dinv[s];
            if (d == s) val += dr * dr;
            hv[4 + j] = (_Float16)val;
        }
        *(half8_t*)(AfP + (size_t)e * 8) = hv;
    }
    __syncthreads();

    float ps;
    layer2<false>(wb,        b1, H, AfP, lane, w);
    layer2<false>(wb + 4096, b2, H, AfP, lane, w);
    ps = layer2<true>(wb + 8192, b3, H, AfP, lane, w);

    #pragma unroll
    for (int off = 32; off > 0; off >>= 1) ps += __shfl_down(ps, off, 64);
    if (lane == 0) red[w] = ps;
    __syncthreads();
    if (t == 0) y[g] = (red[0] + red[1] + red[2] + red[3]) * (1.0f / 4096.0f);
}

extern "C" void kernel_launch(void* const* d_in, const int* in_sizes, int n_in,
                              void* d_out, int out_size, void* d_ws, size_t ws_size,
                              hipStream_t stream) {
    const float* x  = (const float*)d_in[0];
    const int*   ei = (const int*)  d_in[1];
    const float* W1 = (const float*)d_in[2];
    const float* b1 = (const float*)d_in[3];
    const float* W2 = (const float*)d_in[4];
    const float* b2 = (const float*)d_in[5];
    const float* W3 = (const float*)d_in[6];
    const float* b3 = (const float*)d_in[7];
    float* y = (float*)d_out;
    const int etot = in_sizes[1] / 2;     // 2,048,000

    _Float16* wbp = (_Float16*)d_ws;      // 1536*8 f16 = 24 KB
    hipLaunchKernelGGL(prep_wb, dim3(6), dim3(256), 0, stream, W1, W2, W3, wbp);
    hipLaunchKernelGGL(gcn3_mfma3, dim3(NG), dim3(256), 0, stream,
                       x, ei, wbp, b1, b2, b3, y, etot);
}

// Round 5
// 27.472 us; speedup vs baseline: 1.3831x; 1.3831x over previous
//
#include <hip/hip_runtime.h>

#define NG      4000
#define EPG     512
#define CSTRIDE 35   // ints per Cnt row: 35 % 32 == 3 (odd) -> <=2-way LDS bank conflicts

// ---- prep: p = W1*(W2*(W3*1)); out[0..63]=p, out[64]=b1.q2, out[65]=b2.w3, out[66]=64*sum(b3)
__global__ __launch_bounds__(256) void prep_vec(
    const float* __restrict__ W1, const float* __restrict__ b1,
    const float* __restrict__ W2, const float* __restrict__ b2,
    const float* __restrict__ W3, const float* __restrict__ b3,
    float* __restrict__ out)
{
    __shared__ float M[4096];
    __shared__ float w3[64], q2[64];
    const int t = threadIdx.x;
    const int row = t >> 2, q = t & 3;

    // stage W3 (coalesced), row-sum -> w3
    for (int i = t; i < 1024; i += 256) ((float4*)M)[i] = ((const float4*)W3)[i];
    __syncthreads();
    {
        float acc = 0.f;
        #pragma unroll
        for (int i = 0; i < 16; ++i) acc += M[row * 64 + q * 16 + i];
        acc += __shfl_down(acc, 2, 4);
        acc += __shfl_down(acc, 1, 4);
        if (q == 0) w3[row] = acc;
    }
    __syncthreads();

    // stage W2, q2 = W2 * w3
    for (int i = t; i < 1024; i += 256) ((float4*)M)[i] = ((const float4*)W2)[i];
    __syncthreads();
    {
        float acc = 0.f;
        #pragma unroll
        for (int i = 0; i < 16; ++i) {
            const int c = q * 16 + i;
            acc += M[row * 64 + c] * w3[c];
        }
        acc += __shfl_down(acc, 2, 4);
        acc += __shfl_down(acc, 1, 4);
        if (q == 0) q2[row] = acc;
    }
    __syncthreads();

    // stage W1, p = W1 * q2
    for (int i = t; i < 1024; i += 256) ((float4*)M)[i] = ((const float4*)W1)[i];
    __syncthreads();
    {
        float acc = 0.f;
        #pragma unroll
        for (int i = 0; i < 16; ++i) {
            const int c = q * 16 + i;
            acc += M[row * 64 + c] * q2[c];
        }
        acc += __shfl_down(acc, 2, 4);
        acc += __shfl_down(acc, 1, 4);
        if (q == 0) out[row] = acc;
    }

    // scalars (one wave)
    if (t < 64) {
        float t1 = b1[t] * q2[t];
        float t2 = b2[t] * w3[t];
        float t3 = b3[t];
        #pragma unroll
        for (int off = 32; off > 0; off >>= 1) {
            t1 += __shfl_down(t1, off, 64);
            t2 += __shfl_down(t2, off, 64);
            t3 += __shfl_down(t3, off, 64);
        }
        if (t == 0) { out[64] = t1; out[65] = t2; out[66] = 64.f * t3; }
    }
}

// ---- main: per graph, y = (u3 . (x*p) + s2*beta1 + s1*beta2 + beta3) / 4096
__global__ __launch_bounds__(256, 4) void gcn3_collapse(
    const float* __restrict__ x, const int* __restrict__ ei,
    const float* __restrict__ pv, float* __restrict__ y, int etot)
{
    __shared__ int   Cnt[64 * CSTRIDE];   // packed u16x2 counts, Cnt[s][d]
    __shared__ int   deg[64];
    __shared__ float dinv[64], zd[64], u1[64], u2[64], u3[64], xp[64];

    const int g = blockIdx.x, t = threadIdx.x;
    const int base = g * 64;
    const int row = t >> 2, q4 = t & 3;

    // issue x loads early (each thread: 64 contiguous bytes of its row slice)
    const float4* xg = (const float4*)(x + (size_t)g * 4096 + row * 64 + q4 * 16);
    const float4 xr0 = xg[0], xr1 = xg[1], xr2 = xg[2], xr3 = xg[3];

    // p slice (global, L1-hot across all blocks)
    const float4* pp = (const float4*)(pv + q4 * 16);
    const float4 p0 = pp[0], p1 = pp[1], p2 = pp[2], p3 = pp[3];

    // edges (2 per thread)
    const int2 sv = *(const int2*)(ei + (size_t)g * EPG + 2 * t);
    const int2 dv = *(const int2*)(ei + (size_t)etot + (size_t)g * EPG + 2 * t);

    // zero Cnt + deg
    {
        const int4 z = {0, 0, 0, 0};
        int4* c4 = (int4*)Cnt;
        #pragma unroll 1
        for (int i = t; i < (64 * CSTRIDE) / 4; i += 256) c4[i] = z;
        if (t < 64) deg[t] = 0;
    }
    __syncthreads();

    // deterministic integer scatter
    {
        const int sa = sv.x - base, da = dv.x - base;
        const int sb = sv.y - base, db = dv.y - base;
        atomicAdd(&deg[da], 1);
        atomicAdd(&deg[db], 1);
        atomicAdd(&Cnt[sa * CSTRIDE + (da >> 1)], 1 << ((da & 1) * 16));
        atomicAdd(&Cnt[sb * CSTRIDE + (db >> 1)], 1 << ((db & 1) * 16));
    }

    // xp[i] = dot(x[i,:], p) — pure register math, deterministic shfl reduce
    {
        float part = xr0.x * p0.x + xr0.y * p0.y + xr0.z * p0.z + xr0.w * p0.w
                   + xr1.x * p1.x + xr1.y * p1.y + xr1.z * p1.z + xr1.w * p1.w
                   + xr2.x * p2.x + xr2.y * p2.y + xr2.z * p2.z + xr2.w * p2.w
                   + xr3.x * p3.x + xr3.y * p3.y + xr3.z * p3.z + xr3.w * p3.w;
        part += __shfl_down(part, 2, 4);
        part += __shfl_down(part, 1, 4);
        if (q4 == 0) xp[row] = part;
    }
    __syncthreads();

    if (t < 64) {
        const float di = rsqrtf((float)(deg[t] + 1));   // +1 = self-loop
        dinv[t] = di;
        zd[t] = di;                                     // zd = dinv * z, z = 1
    }
    __syncthreads();

    // u[s] = dinv[s] * sum_d cnt(s,d)*zd[d] + dinv[s]^2 * zprev[s]
    auto upass = [&](float* u, const float* zprev) {
        const int* rp = Cnt + row * CSTRIDE + q4 * 8;
        float acc = 0.f;
        #pragma unroll
        for (int i = 0; i < 8; ++i) {
            const unsigned v = (unsigned)rp[i];
            const int d0 = q4 * 16 + 2 * i;
            acc += (float)(v & 0xffffu) * zd[d0];
            acc += (float)(v >> 16)     * zd[d0 + 1];
        }
        acc += __shfl_down(acc, 2, 4);
        acc += __shfl_down(acc, 1, 4);
        if (q4 == 0) {
            const float di = dinv[row];
            const float zp = zprev ? zprev[row] : 1.0f;
            u[row] = di * acc + di * di * zp;
        }
    };

    upass(u1, nullptr);
    __syncthreads();
    if (t < 64) zd[t] = dinv[t] * u1[t];
    __syncthreads();
    upass(u2, u1);
    __syncthreads();
    if (t < 64) zd[t] = dinv[t] * u2[t];
    __syncthreads();
    upass(u3, u2);
    __syncthreads();

    // final: r = u3 . xp, s1 = sum(u1), s2 = sum(u2)
    if (t < 64) {
        float r  = u3[t] * xp[t];
        float a1 = u1[t];
        float a2 = u2[t];
        #pragma unroll
        for (int off = 32; off > 0; off >>= 1) {
            r  += __shfl_down(r,  off, 64);
            a1 += __shfl_down(a1, off, 64);
            a2 += __shfl_down(a2, off, 64);
        }
        if (t == 0) {
            const float beta1 = pv[64], beta2 = pv[65], beta3 = pv[66];
            y[g] = (r + a2 * beta1 + a1 * beta2 + beta3) * (1.0f / 4096.0f);
        }
    }
}

extern "C" void kernel_launch(void* const* d_in, const int* in_sizes, int n_in,
                              void* d_out, int out_size, void* d_ws, size_t ws_size,
                              hipStream_t stream) {
    const float* x  = (const float*)d_in[0];
    const int*   ei = (const int*)  d_in[1];
    const float* W1 = (const float*)d_in[2];
    const float* b1 = (const float*)d_in[3];
    const float* W2 = (const float*)d_in[4];
    const float* b2 = (const float*)d_in[5];
    const float* W3 = (const float*)d_in[6];
    const float* b3 = (const float*)d_in[7];
    float* y = (float*)d_out;
    const int etot = in_sizes[1] / 2;     // 2,048,000

    float* pv = (float*)d_ws;             // 67 floats
    hipLaunchKernelGGL(prep_vec, dim3(1), dim3(256), 0, stream,
                       W1, b1, W2, b2, W3, b3, pv);
    hipLaunchKernelGGL(gcn3_collapse, dim3(NG), dim3(256), 0, stream,
                       x, ei, pv, y, etot);
}